// Round 8
// baseline (506.976 us; speedup 1.0000x reference)
//
#include <hip/hip_runtime.h>
#include <hip/hip_cooperative_groups.h>

namespace cg = cooperative_groups;

// x [B=16, N=1024, F=256] fp32.  Algebra:
//   U2 = x@(Wr@Wu)^T + Wr@bu
//   M2t[b][j][k] = sum_i U2[b,i,j] * beta[b,i,k]
//   out[m,j] = (alpha[m,:].M2t[b][j,:] - d[m]*U2[m,j]) / N + x[m,j]
// Single cooperative kernel, 512 blocks x 256 thr (2 blocks/CU co-resident):
//   P0 prep(weights) | sync | P1 proj3 | sync | P2 m2 | sync | P3 final

typedef __bf16 bf16;
typedef float floatx4 __attribute__((ext_vector_type(4)));
typedef bf16 bf16x8 __attribute__((ext_vector_type(8)));
typedef bf16 bf16x4 __attribute__((ext_vector_type(4)));

constexpr int FD = 256;
constexpr int NB = 16;
constexpr int NN = 1024;
constexpr int RR = NB * NN;   // 16384

__device__ __forceinline__ bf16x8 cvt8(float4 a, float4 b) {
    bf16x8 o = { (bf16)a.x, (bf16)a.y, (bf16)a.z, (bf16)a.w,
                 (bf16)b.x, (bf16)b.y, (bf16)b.z, (bf16)b.w };
    return o;
}

// ---------------- P0: prep (weights only) ----------------
// blk [0,16): cvt Wa/Wb | [16,80): Wc 4 rows/blk | 80: bc
__device__ __forceinline__ void dev_prep(int blk, int tid,
    const float* __restrict__ Wa, const float* __restrict__ Wb,
    const float* __restrict__ Wu, const float* __restrict__ bu, const float* __restrict__ Wr,
    bf16* __restrict__ Wab, bf16* __restrict__ Wbb, bf16* __restrict__ Wcb, float* __restrict__ bc)
{
    if (blk < 16) {
        int w = blk >> 3, wb = blk & 7;
        const float* src = (w == 0) ? Wa : Wb;
        bf16* dst = (w == 0) ? Wab : Wbb;
        for (int it = 0; it < 8; it++) {
            int i = wb * 8192 + it * 1024 + tid * 4;
            float4 v = *(const float4*)&src[i];
            bf16x4 o = { (bf16)v.x, (bf16)v.y, (bf16)v.z, (bf16)v.w };
            *(bf16x4*)&dst[i] = o;
        }
    } else if (blk < 80) {
        int j0 = (blk - 16) * 4;
        float acc[4] = {};
        for (int g = 0; g < FD; g++) {
            float wu = Wu[g * FD + tid];
            #pragma unroll
            for (int jr = 0; jr < 4; jr++)
                acc[jr] += Wr[(j0 + jr) * FD + g] * wu;
        }
        #pragma unroll
        for (int jr = 0; jr < 4; jr++)
            Wcb[(j0 + jr) * FD + tid] = (bf16)acc[jr];
    } else if (blk == 80) {
        float s = 0.0f;
        for (int g = 0; g < FD; g++) s += Wr[tid * FD + g] * bu[g];
        bc[tid] = s;
    }
}

// ---------------- P1: proj3 (BM=128, BN=64, BK=32, LDK=36; x fp32 inline cvt) ----------------
__device__ __forceinline__ void dev_proj(int bx, int by, int tid, char* smemraw,
    const float* __restrict__ x,
    const bf16* __restrict__ Wab, const bf16* __restrict__ Wbb, const bf16* __restrict__ Wcb,
    const float* __restrict__ bc,
    bf16* __restrict__ alpha, bf16* __restrict__ U2,
    bf16* __restrict__ betaT, bf16* __restrict__ U2T, float* __restrict__ dpart)
{
    constexpr int LDK = 36;
    bf16* As = (bf16*)smemraw;              // [128][36]  9216 B
    bf16* Bs = (bf16*)(smemraw + 9216);     // [3][64][36] 13824 B
    bf16* Tr = (bf16*)(smemraw + 23040);    // 8960 elems 17920 B
    const int wave = tid >> 6, lane = tid & 63;
    const int q = lane >> 4, l16 = lane & 15;
    const int bm = by * 128, bn = bx * 64;

    const int rowA0 = tid >> 2, k8A = (tid & 3) * 8;
    const int rowA1 = rowA0 + 64;
    const int rowW = tid >> 2, k8W = (tid & 3) * 8;

    bf16x8 pxa0, pxa1; int4 pwa, pwb, pwc;
#define PLOAD(KK) do { \
        const float* s0 = &x[(size_t)(bm + rowA0) * FD + (KK) + k8A]; \
        pxa0 = cvt8(*(const float4*)s0, *(const float4*)(s0 + 4)); \
        const float* s1 = &x[(size_t)(bm + rowA1) * FD + (KK) + k8A]; \
        pxa1 = cvt8(*(const float4*)s1, *(const float4*)(s1 + 4)); \
        pwa = *(const int4*)&Wab[(size_t)(bn + rowW) * FD + (KK) + k8W]; \
        pwb = *(const int4*)&Wbb[(size_t)(bn + rowW) * FD + (KK) + k8W]; \
        pwc = *(const int4*)&Wcb[(size_t)(bn + rowW) * FD + (KK) + k8W]; \
    } while (0)

    floatx4 acc[3][2][4] = {};
    PLOAD(0);

    for (int k0 = 0; k0 < FD; k0 += 32) {
        *(bf16x8*)&As[rowA0 * LDK + k8A] = pxa0;
        *(bf16x8*)&As[rowA1 * LDK + k8A] = pxa1;
        *(int4*)&Bs[(0 * 64 + rowW) * LDK + k8W] = pwa;
        *(int4*)&Bs[(1 * 64 + rowW) * LDK + k8W] = pwb;
        *(int4*)&Bs[(2 * 64 + rowW) * LDK + k8W] = pwc;
        __syncthreads();
        if (k0 + 32 < FD) PLOAD(k0 + 32);
        bf16x8 af[2];
        #pragma unroll
        for (int mi = 0; mi < 2; mi++)
            af[mi] = *(const bf16x8*)&As[(wave * 32 + mi * 16 + l16) * LDK + q * 8];
        #pragma unroll
        for (int w = 0; w < 3; w++) {
            bf16x8 bq[4];
            #pragma unroll
            for (int nj = 0; nj < 4; nj++)
                bq[nj] = *(const bf16x8*)&Bs[(w * 64 + nj * 16 + l16) * LDK + q * 8];
            #pragma unroll
            for (int mi = 0; mi < 2; mi++)
                #pragma unroll
                for (int nj = 0; nj < 4; nj++)
                    acc[w][mi][nj] = __builtin_amdgcn_mfma_f32_16x16x32_bf16(af[mi], bq[nj], acc[w][mi][nj], 0, 0, 0);
        }
        __syncthreads();
    }
#undef PLOAD

    const int b = bm >> 10, n0 = bm & (NN - 1);
    float bcv[4];
    #pragma unroll
    for (int nj = 0; nj < 4; nj++) bcv[nj] = bc[bn + nj * 16 + l16];

    // diag partials
    #pragma unroll
    for (int mi = 0; mi < 2; mi++)
        #pragma unroll
        for (int i = 0; i < 4; i++) {
            float p = 0.0f;
            #pragma unroll
            for (int nj = 0; nj < 4; nj++)
                p += acc[0][mi][nj][i] * acc[1][mi][nj][i];
            #pragma unroll
            for (int off = 1; off < 16; off <<= 1) p += __shfl_xor(p, off);
            if (l16 == 0) {
                int m = bm + wave * 32 + mi * 16 + q * 4 + i;
                dpart[(size_t)bx * RR + m] = p;
            }
        }

    // natural outputs via [128][68] repack: alpha (w=0), U2 (w=2 +bc)
    #pragma unroll
    for (int pass = 0; pass < 2; pass++) {
        const int w = pass ? 2 : 0;
        __syncthreads();
        #pragma unroll
        for (int mi = 0; mi < 2; mi++)
            #pragma unroll
            for (int i = 0; i < 4; i++) {
                int ml = wave * 32 + mi * 16 + q * 4 + i;
                #pragma unroll
                for (int nj = 0; nj < 4; nj++) {
                    float v = acc[w][mi][nj][i];
                    if (w == 2) v += bcv[nj];
                    Tr[ml * 68 + nj * 16 + l16] = (bf16)v;
                }
            }
        __syncthreads();
        bf16* dst = pass ? U2 : alpha;
        #pragma unroll
        for (int it = 0; it < 4; it++) {
            int c = tid + it * 256;
            int row = c >> 3, chunk = c & 7;
            bf16x8 v = *(const bf16x8*)&Tr[row * 68 + chunk * 8];
            *(bf16x8*)&dst[(size_t)(bm + row) * FD + bn + chunk * 8] = v;
        }
    }

    // transposed outputs via [64][140] repack: betaT (w=1), U2T (w=2 +bc)
    #pragma unroll
    for (int pass = 0; pass < 2; pass++) {
        const int w = pass ? 2 : 1;
        __syncthreads();
        #pragma unroll
        for (int mi = 0; mi < 2; mi++)
            #pragma unroll
            for (int nj = 0; nj < 4; nj++) {
                bf16x4 v4;
                #pragma unroll
                for (int i = 0; i < 4; i++) {
                    float v = acc[w][mi][nj][i];
                    if (w == 2) v += bcv[nj];
                    v4[i] = (bf16)v;
                }
                *(bf16x4*)&Tr[(nj * 16 + l16) * 140 + wave * 32 + mi * 16 + q * 4] = v4;
            }
        __syncthreads();
        bf16* dst = (pass ? U2T : betaT) + (size_t)b * FD * NN;
        #pragma unroll
        for (int it = 0; it < 4; it++) {
            int c = tid + it * 256;
            int row = c >> 4, chunk = c & 15;
            bf16x8 v = *(const bf16x8*)&Tr[row * 140 + chunk * 8];
            *(bf16x8*)&dst[(size_t)(bn + row) * NN + n0 + chunk * 8] = v;
        }
    }
}

// ---------------- P2: m2 (BK=64; 256 tiles) ----------------
__device__ __forceinline__ void dev_m2(int blk, int tid, char* smemraw,
    const bf16* __restrict__ U2T, const bf16* __restrict__ betaT, bf16* __restrict__ M2t)
{
    constexpr int LDK = 68;
    bf16* As = (bf16*)smemraw;              // 64*68  8704 B
    bf16* Bs = (bf16*)(smemraw + 8704);
    bf16* Tr = (bf16*)(smemraw + 17408);    // 64*68
    const int wave = tid >> 6, lane = tid & 63;
    const int q = lane >> 4, l16 = lane & 15;
    const int wj = wave >> 1, wk = wave & 1;
    const int b = blk >> 4, rem = blk & 15;
    const int bj = (rem >> 2) * 64, bk = (rem & 3) * 64;
    const int row0 = tid >> 3, k8 = (tid & 7) * 8;
    const bf16* Ap = U2T + (size_t)b * FD * NN;
    const bf16* Bp = betaT + (size_t)b * FD * NN;

    int4 ra[2], rb[2];
    ra[0] = *(const int4*)&Ap[(size_t)(bj + row0) * NN + k8];
    ra[1] = *(const int4*)&Ap[(size_t)(bj + row0 + 32) * NN + k8];
    rb[0] = *(const int4*)&Bp[(size_t)(bk + row0) * NN + k8];
    rb[1] = *(const int4*)&Bp[(size_t)(bk + row0 + 32) * NN + k8];

    floatx4 acc[2][2] = {};
    for (int n0 = 0; n0 < NN; n0 += 64) {
        *(int4*)&As[row0 * LDK + k8] = ra[0];
        *(int4*)&As[(row0 + 32) * LDK + k8] = ra[1];
        *(int4*)&Bs[row0 * LDK + k8] = rb[0];
        *(int4*)&Bs[(row0 + 32) * LDK + k8] = rb[1];
        __syncthreads();
        if (n0 + 64 < NN) {
            ra[0] = *(const int4*)&Ap[(size_t)(bj + row0) * NN + n0 + 64 + k8];
            ra[1] = *(const int4*)&Ap[(size_t)(bj + row0 + 32) * NN + n0 + 64 + k8];
            rb[0] = *(const int4*)&Bp[(size_t)(bk + row0) * NN + n0 + 64 + k8];
            rb[1] = *(const int4*)&Bp[(size_t)(bk + row0 + 32) * NN + n0 + 64 + k8];
        }
        #pragma unroll
        for (int h = 0; h < 2; h++) {
            bf16x8 af[2], bq[2];
            #pragma unroll
            for (int mi = 0; mi < 2; mi++)
                af[mi] = *(const bf16x8*)&As[(wj * 32 + mi * 16 + l16) * LDK + h * 32 + q * 8];
            #pragma unroll
            for (int kj = 0; kj < 2; kj++)
                bq[kj] = *(const bf16x8*)&Bs[(wk * 32 + kj * 16 + l16) * LDK + h * 32 + q * 8];
            #pragma unroll
            for (int mi = 0; mi < 2; mi++)
                #pragma unroll
                for (int kj = 0; kj < 2; kj++)
                    acc[mi][kj] = __builtin_amdgcn_mfma_f32_16x16x32_bf16(af[mi], bq[kj], acc[mi][kj], 0, 0, 0);
        }
        __syncthreads();
    }
    __syncthreads();
    #pragma unroll
    for (int mi = 0; mi < 2; mi++)
        #pragma unroll
        for (int i = 0; i < 4; i++) {
            int jl = wj * 32 + mi * 16 + q * 4 + i;
            #pragma unroll
            for (int kj = 0; kj < 2; kj++)
                Tr[jl * 68 + wk * 32 + kj * 16 + l16] = (bf16)acc[mi][kj][i];
        }
    __syncthreads();
    bf16* Mb = M2t + (size_t)b * FD * FD;
    #pragma unroll
    for (int it = 0; it < 2; it++) {
        int c = tid + it * 256;
        int r = c >> 3, chunk = c & 7;
        bf16x8 v = *(const bf16x8*)&Tr[r * 68 + chunk * 8];
        *(bf16x8*)&Mb[(size_t)(bj + r) * FD + bk + chunk * 8] = v;
    }
}

// ---------------- P3: final (BM=128, BN=64, BK=32) ----------------
__device__ __forceinline__ void dev_final(int bx, int by, int tid, char* smemraw,
    const bf16* __restrict__ alpha, const bf16* __restrict__ M2t,
    const float* __restrict__ dpart, const bf16* __restrict__ U2,
    const float* __restrict__ x, float* __restrict__ out)
{
    constexpr int LDK = 36;
    bf16* As = (bf16*)smemraw;             // [128][36]
    bf16* Bs = (bf16*)(smemraw + 9216);    // [64][36]
    const int wave = tid >> 6, lane = tid & 63;
    const int q = lane >> 4, l16 = lane & 15;
    const int bm = by * 128, bn = bx * 64;
    const bf16* Qb = M2t + (size_t)(bm >> 10) * FD * FD;

    const int rowA0 = tid >> 2, k8A = (tid & 3) * 8;
    const int rowA1 = rowA0 + 64;
    const int rowB = tid >> 2, k8B = (tid & 3) * 8;

    int4 ra0 = *(const int4*)&alpha[(size_t)(bm + rowA0) * FD + k8A];
    int4 ra1 = *(const int4*)&alpha[(size_t)(bm + rowA1) * FD + k8A];
    int4 rb  = *(const int4*)&Qb[(size_t)(bn + rowB) * FD + k8B];

    floatx4 acc[2][4] = {};
    for (int k0 = 0; k0 < FD; k0 += 32) {
        *(int4*)&As[rowA0 * LDK + k8A] = ra0;
        *(int4*)&As[rowA1 * LDK + k8A] = ra1;
        *(int4*)&Bs[rowB * LDK + k8B] = rb;
        __syncthreads();
        if (k0 + 32 < FD) {
            ra0 = *(const int4*)&alpha[(size_t)(bm + rowA0) * FD + k0 + 32 + k8A];
            ra1 = *(const int4*)&alpha[(size_t)(bm + rowA1) * FD + k0 + 32 + k8A];
            rb  = *(const int4*)&Qb[(size_t)(bn + rowB) * FD + k0 + 32 + k8B];
        }
        bf16x8 af[2], bq[4];
        #pragma unroll
        for (int mi = 0; mi < 2; mi++)
            af[mi] = *(const bf16x8*)&As[(wave * 32 + mi * 16 + l16) * LDK + q * 8];
        #pragma unroll
        for (int nj = 0; nj < 4; nj++)
            bq[nj] = *(const bf16x8*)&Bs[(nj * 16 + l16) * LDK + q * 8];
        #pragma unroll
        for (int mi = 0; mi < 2; mi++)
            #pragma unroll
            for (int nj = 0; nj < 4; nj++)
                acc[mi][nj] = __builtin_amdgcn_mfma_f32_16x16x32_bf16(af[mi], bq[nj], acc[mi][nj], 0, 0, 0);
        __syncthreads();
    }

    #pragma unroll
    for (int mi = 0; mi < 2; mi++)
        #pragma unroll
        for (int i = 0; i < 4; i++) {
            int m = bm + wave * 32 + mi * 16 + q * 4 + i;
            float d = dpart[m] + dpart[RR + m] + dpart[2 * RR + m] + dpart[3 * RR + m];
            #pragma unroll
            for (int nj = 0; nj < 4; nj++) {
                int n = bn + nj * 16 + l16;
                float v = (acc[mi][nj][i] - d * (float)U2[(size_t)m * FD + n]) * (1.0f / 1024.0f);
                out[(size_t)m * FD + n] = v + x[(size_t)m * FD + n];
            }
        }
}

// ---------------- fused cooperative kernel ----------------
__global__ __launch_bounds__(256, 2)
void fused(const float* x, const float* Wa, const float* Wb, const float* Wu,
           const float* bu, const float* Wr,
           bf16* Wab, bf16* Wbb, bf16* Wcb, float* bc,
           bf16* alpha, bf16* U2, bf16* betaT, bf16* U2T, bf16* M2t,
           float* dpart, float* out)
{
    __shared__ __align__(16) char smem[40960];
    cg::grid_group grid = cg::this_grid();
    const int blk = blockIdx.x, tid = threadIdx.x;

    dev_prep(blk, tid, Wa, Wb, Wu, bu, Wr, Wab, Wbb, Wcb, bc);
    __threadfence();
    grid.sync();

    dev_proj(blk & 3, blk >> 2, tid, smem, x, Wab, Wbb, Wcb, bc, alpha, U2, betaT, U2T, dpart);
    __threadfence();
    grid.sync();

    if (blk < 256) dev_m2(blk, tid, smem, U2T, betaT, M2t);
    __threadfence();
    grid.sync();

    dev_final(blk & 3, blk >> 2, tid, smem, alpha, M2t, dpart, U2, x, out);
}

// ---------------- fallback kernels (classic 4-dispatch path) ----------------
__global__ __launch_bounds__(256)
void prep_k(const float* Wa, const float* Wb, const float* Wu, const float* bu, const float* Wr,
            bf16* Wab, bf16* Wbb, bf16* Wcb, float* bc)
{
    dev_prep(blockIdx.x, threadIdx.x, Wa, Wb, Wu, bu, Wr, Wab, Wbb, Wcb, bc);
}

__global__ __launch_bounds__(256)
void proj_k(const float* x, const bf16* Wab, const bf16* Wbb, const bf16* Wcb, const float* bc,
            bf16* alpha, bf16* U2, bf16* betaT, bf16* U2T, float* dpart)
{
    __shared__ __align__(16) char smem[40960];
    dev_proj(blockIdx.x, blockIdx.y, threadIdx.x, smem, x, Wab, Wbb, Wcb, bc, alpha, U2, betaT, U2T, dpart);
}

__global__ __launch_bounds__(256)
void m2_k(const bf16* U2T, const bf16* betaT, bf16* M2t)
{
    __shared__ __align__(16) char smem[26112];
    dev_m2(blockIdx.x, threadIdx.x, smem, U2T, betaT, M2t);
}

__global__ __launch_bounds__(256)
void final_k(const bf16* alpha, const bf16* M2t, const float* dpart, const bf16* U2,
             const float* x, float* out)
{
    __shared__ __align__(16) char smem[13824];
    dev_final(blockIdx.x, blockIdx.y, threadIdx.x, smem, alpha, M2t, dpart, U2, x, out);
}

extern "C" void kernel_launch(void* const* d_in, const int* in_sizes, int n_in,
                              void* d_out, int out_size, void* d_ws, size_t ws_size,
                              hipStream_t stream)
{
    const float* x  = (const float*)d_in[0];
    const float* Wa = (const float*)d_in[1];
    const float* Wb = (const float*)d_in[2];
    const float* Wu = (const float*)d_in[3];
    const float* bu = (const float*)d_in[4];
    const float* Wr = (const float*)d_in[5];
    float* out = (float*)d_out;

    char* w = (char*)d_ws;
    bf16* Wab   = (bf16*)w;  w += (size_t)FD * FD * 2;
    bf16* Wbb   = (bf16*)w;  w += (size_t)FD * FD * 2;
    bf16* Wcb   = (bf16*)w;  w += (size_t)FD * FD * 2;
    float* bc   = (float*)w; w += (size_t)FD * 4;
    bf16* alpha = (bf16*)w;  w += (size_t)RR * FD * 2;
    bf16* U2    = (bf16*)w;  w += (size_t)RR * FD * 2;
    bf16* betaT = (bf16*)w;  w += (size_t)RR * FD * 2;
    bf16* U2T   = (bf16*)w;  w += (size_t)RR * FD * 2;
    bf16* M2t   = (bf16*)w;  w += (size_t)NB * FD * FD * 2;
    float* dpart= (float*)w; w += (size_t)4 * RR * 4;

    void* args[] = { (void*)&x, (void*)&Wa, (void*)&Wb, (void*)&Wu, (void*)&bu, (void*)&Wr,
                     (void*)&Wab, (void*)&Wbb, (void*)&Wcb, (void*)&bc,
                     (void*)&alpha, (void*)&U2, (void*)&betaT, (void*)&U2T, (void*)&M2t,
                     (void*)&dpart, (void*)&out };

    hipError_t err = hipLaunchCooperativeKernel((const void*)fused, dim3(512), dim3(256),
                                                args, 0, stream);
    if (err != hipSuccess) {
        // deterministic fallback: classic 4-dispatch pipeline
        prep_k<<<dim3(81), dim3(256), 0, stream>>>(Wa, Wb, Wu, bu, Wr, Wab, Wbb, Wcb, bc);
        proj_k<<<dim3(4, 128), dim3(256), 0, stream>>>(x, Wab, Wbb, Wcb, bc,
                                                       alpha, U2, betaT, U2T, dpart);
        m2_k<<<dim3(256), dim3(256), 0, stream>>>(U2T, betaT, M2t);
        final_k<<<dim3(4, 128), dim3(256), 0, stream>>>(alpha, M2t, dpart, U2, x, out);
    }
}

// Round 9
// 143.365 us; speedup vs baseline: 3.5363x; 3.5363x over previous
//
#include <hip/hip_runtime.h>

// x [B=16, N=1024, F=256] fp32.  Algebra:
//   U2 = x@(Wr@Wu)^T + Wr@bu
//   M2t[b][j][k] = sum_i U2[b,i,j] * beta[b,i,k]
//   out[m,j] = (alpha[m,:].M2t[b][j,:] - d[m]*U2[m,j]) / N + x[m,j]
// K1 prep : Wcb = bf16(Wr@Wu); bc = Wr@bu   (Wa/Wb/x converted inline in proj3)
// K2 proj3: BM=128 BK=32 LDK=36, XCD-swizzled 1D grid 512
// K3 m2   : BK=64, LDS-aliased repack, XCD-swizzled 1D grid 256
// K4 final: BM=128 BK=32, XCD-swizzled 1D grid 512
// dur_us carries a fixed ~84us harness fill floor; kernel-side target ~32us.

typedef __bf16 bf16;
typedef float floatx4 __attribute__((ext_vector_type(4)));
typedef bf16 bf16x8 __attribute__((ext_vector_type(8)));
typedef bf16 bf16x4 __attribute__((ext_vector_type(4)));

constexpr int FD = 256;
constexpr int NB = 16;
constexpr int NN = 1024;
constexpr int RR = NB * NN;   // 16384

__device__ __forceinline__ bf16x8 cvt8(float4 a, float4 b) {
    bf16x8 o = { (bf16)a.x, (bf16)a.y, (bf16)a.z, (bf16)a.w,
                 (bf16)b.x, (bf16)b.y, (bf16)b.z, (bf16)b.w };
    return o;
}

// ---------------- K1: prep ----------------
__global__ __launch_bounds__(256)
void prep(const float* __restrict__ Wu, const float* __restrict__ bu, const float* __restrict__ Wr,
          bf16* __restrict__ Wcb, float* __restrict__ bc)
{
    const int blk = blockIdx.x, tid = threadIdx.x;
    if (blk < 256) {  // Wc[j][f] = sum_g Wr[j][g]*Wu[g][f]; one j per block
        const int j = blk;
        float acc = 0.0f;
        for (int g = 0; g < FD; g += 4) {
            float4 wr = *(const float4*)&Wr[j * FD + g];
            acc += wr.x * Wu[g * FD + tid] + wr.y * Wu[(g + 1) * FD + tid]
                 + wr.z * Wu[(g + 2) * FD + tid] + wr.w * Wu[(g + 3) * FD + tid];
        }
        Wcb[j * FD + tid] = (bf16)acc;
    } else {  // bc[j] = Wr[j,:].bu
        float s = 0.0f;
        for (int g = 0; g < FD; g++) s += Wr[tid * FD + g] * bu[g];
        bc[tid] = s;
    }
}

// ---------------- K2: proj3 (R4 body; XCD-swizzled 1D grid) ----------------
// swizzle: by = id & 127, bx = id >> 7  ->  the 4 bx-blocks of one row-tile share
// id mod 8 (128 = 0 mod 8) hence (assumed round-robin) the same XCD L2.
__global__ __launch_bounds__(256)
void proj3(const float* __restrict__ x,
           const float* __restrict__ Wa, const float* __restrict__ Wb, const bf16* __restrict__ Wc,
           bf16* __restrict__ alpha, bf16* __restrict__ U2,
           bf16* __restrict__ betaT, bf16* __restrict__ U2T,
           const float* __restrict__ bc, float* __restrict__ dpart)
{
    constexpr int BM = 128, BN = 64, BK = 32, LDK = 36;
    __shared__ bf16 As[BM][LDK];
    __shared__ bf16 Bs[3][BN][LDK];
    __shared__ bf16 Tr[8960];   // natural [128][68] (8704) / transposed [64][140] (8960)
    const int tid = threadIdx.x;
    const int wave = tid >> 6, lane = tid & 63;
    const int q = lane >> 4, l16 = lane & 15;
    const int id = blockIdx.x;
    const int by = id & 127, bx = id >> 7;
    const int bm = by * BM, bn = bx * BN;

    const int rowA0 = tid >> 2,          k8A0 = (tid & 3) * 8;
    const int rowA1 = (tid + 256) >> 2,  k8A1 = (tid & 3) * 8;
    const int rowW  = tid >> 2,          k8W  = (tid & 3) * 8;

    bf16x8 pxa0, pxa1, pwa, pwb; int4 pwc;
#define PROJ_LOAD(KK) do { \
        const float* s0 = &x[(size_t)(bm + rowA0) * FD + (KK) + k8A0]; \
        pxa0 = cvt8(*(const float4*)s0, *(const float4*)(s0 + 4)); \
        const float* s1 = &x[(size_t)(bm + rowA1) * FD + (KK) + k8A1]; \
        pxa1 = cvt8(*(const float4*)s1, *(const float4*)(s1 + 4)); \
        const float* sa = &Wa[(size_t)(bn + rowW) * FD + (KK) + k8W]; \
        pwa = cvt8(*(const float4*)sa, *(const float4*)(sa + 4)); \
        const float* sb = &Wb[(size_t)(bn + rowW) * FD + (KK) + k8W]; \
        pwb = cvt8(*(const float4*)sb, *(const float4*)(sb + 4)); \
        pwc = *(const int4*)&Wc[(size_t)(bn + rowW) * FD + (KK) + k8W]; \
    } while (0)

    floatx4 acc[3][2][4] = {};
    PROJ_LOAD(0);

    for (int k0 = 0; k0 < FD; k0 += BK) {
        *(bf16x8*)&As[rowA0][k8A0] = pxa0;
        *(bf16x8*)&As[rowA1][k8A1] = pxa1;
        *(bf16x8*)&Bs[0][rowW][k8W] = pwa;
        *(bf16x8*)&Bs[1][rowW][k8W] = pwb;
        *(int4*)&Bs[2][rowW][k8W] = pwc;
        __syncthreads();
        if (k0 + BK < FD) PROJ_LOAD(k0 + BK);
        bf16x8 af[2];
        #pragma unroll
        for (int mi = 0; mi < 2; mi++)
            af[mi] = *(const bf16x8*)&As[wave * 32 + mi * 16 + l16][q * 8];
        #pragma unroll
        for (int w = 0; w < 3; w++) {
            bf16x8 bq[4];
            #pragma unroll
            for (int nj = 0; nj < 4; nj++)
                bq[nj] = *(const bf16x8*)&Bs[w][nj * 16 + l16][q * 8];
            #pragma unroll
            for (int mi = 0; mi < 2; mi++)
                #pragma unroll
                for (int nj = 0; nj < 4; nj++)
                    acc[w][mi][nj] = __builtin_amdgcn_mfma_f32_16x16x32_bf16(af[mi], bq[nj], acc[w][mi][nj], 0, 0, 0);
        }
        __syncthreads();
    }
#undef PROJ_LOAD

    const int b = bm >> 10, n0 = bm & (NN - 1);
    float bcv[4];
    #pragma unroll
    for (int nj = 0; nj < 4; nj++) bcv[nj] = bc[bn + nj * 16 + l16];

    // diag partials
    #pragma unroll
    for (int mi = 0; mi < 2; mi++)
        #pragma unroll
        for (int i = 0; i < 4; i++) {
            float p = 0.0f;
            #pragma unroll
            for (int nj = 0; nj < 4; nj++)
                p += acc[0][mi][nj][i] * acc[1][mi][nj][i];
            #pragma unroll
            for (int off = 1; off < 16; off <<= 1) p += __shfl_xor(p, off);
            if (l16 == 0) {
                int m = bm + wave * 32 + mi * 16 + q * 4 + i;
                dpart[(size_t)bx * RR + m] = p;
            }
        }

    // natural outputs via [128][68] repack: alpha (w=0), U2 (w=2 +bc)
    #pragma unroll
    for (int pass = 0; pass < 2; pass++) {
        const int w = pass ? 2 : 0;
        __syncthreads();
        #pragma unroll
        for (int mi = 0; mi < 2; mi++)
            #pragma unroll
            for (int i = 0; i < 4; i++) {
                int ml = wave * 32 + mi * 16 + q * 4 + i;
                #pragma unroll
                for (int nj = 0; nj < 4; nj++) {
                    float v = acc[w][mi][nj][i];
                    if (w == 2) v += bcv[nj];
                    Tr[ml * 68 + nj * 16 + l16] = (bf16)v;
                }
            }
        __syncthreads();
        bf16* dst = pass ? U2 : alpha;
        #pragma unroll
        for (int it = 0; it < 4; it++) {
            int c = tid + it * 256;
            int row = c >> 3, chunk = c & 7;
            bf16x8 v = *(const bf16x8*)&Tr[row * 68 + chunk * 8];
            *(bf16x8*)&dst[(size_t)(bm + row) * FD + bn + chunk * 8] = v;
        }
    }

    // transposed outputs via [64][140] repack: betaT (w=1), U2T (w=2 +bc)
    #pragma unroll
    for (int pass = 0; pass < 2; pass++) {
        const int w = pass ? 2 : 1;
        __syncthreads();
        #pragma unroll
        for (int mi = 0; mi < 2; mi++)
            #pragma unroll
            for (int nj = 0; nj < 4; nj++) {
                bf16x4 v4;
                #pragma unroll
                for (int i = 0; i < 4; i++) {
                    float v = acc[w][mi][nj][i];
                    if (w == 2) v += bcv[nj];
                    v4[i] = (bf16)v;
                }
                *(bf16x4*)&Tr[(nj * 16 + l16) * 140 + wave * 32 + mi * 16 + q * 4] = v4;
            }
        __syncthreads();
        bf16* dst = (pass ? U2T : betaT) + (size_t)b * FD * NN;
        #pragma unroll
        for (int it = 0; it < 4; it++) {
            int c = tid + it * 256;
            int row = c >> 4, chunk = c & 15;
            bf16x8 v = *(const bf16x8*)&Tr[row * 140 + chunk * 8];
            *(bf16x8*)&dst[(size_t)(bn + row) * NN + n0 + chunk * 8] = v;
        }
    }
}

// ---------------- K3: m2 (BK=64, aliased Tr; XCD-swizzled: b = id & 15) ----------------
__global__ __launch_bounds__(256)
void m2_mfma(const bf16* __restrict__ U2T, const bf16* __restrict__ betaT, bf16* __restrict__ M2t)
{
    constexpr int LDK = 68;
    __shared__ __align__(16) bf16 As[64 * LDK];   // 8704 B
    __shared__ __align__(16) bf16 Bs[64 * LDK];
    bf16* Tr = As;                                // aliased: used only after K-loop barrier
    const int tid = threadIdx.x;
    const int wave = tid >> 6, lane = tid & 63;
    const int q = lane >> 4, l16 = lane & 15;
    const int wj = wave >> 1, wk = wave & 1;
    const int id = blockIdx.x;
    const int b = id & 15, rem = id >> 4;         // 16 tiles of batch b share id mod 8 -> one XCD
    const int bj = (rem >> 2) * 64, bk = (rem & 3) * 64;
    const int row0 = tid >> 3, k8 = (tid & 7) * 8;
    const bf16* Ap = U2T + (size_t)b * FD * NN;
    const bf16* Bp = betaT + (size_t)b * FD * NN;

    int4 ra[2], rb[2];
    ra[0] = *(const int4*)&Ap[(size_t)(bj + row0) * NN + k8];
    ra[1] = *(const int4*)&Ap[(size_t)(bj + row0 + 32) * NN + k8];
    rb[0] = *(const int4*)&Bp[(size_t)(bk + row0) * NN + k8];
    rb[1] = *(const int4*)&Bp[(size_t)(bk + row0 + 32) * NN + k8];

    floatx4 acc[2][2] = {};
    for (int n0 = 0; n0 < NN; n0 += 64) {
        *(int4*)&As[row0 * LDK + k8] = ra[0];
        *(int4*)&As[(row0 + 32) * LDK + k8] = ra[1];
        *(int4*)&Bs[row0 * LDK + k8] = rb[0];
        *(int4*)&Bs[(row0 + 32) * LDK + k8] = rb[1];
        __syncthreads();
        if (n0 + 64 < NN) {
            ra[0] = *(const int4*)&Ap[(size_t)(bj + row0) * NN + n0 + 64 + k8];
            ra[1] = *(const int4*)&Ap[(size_t)(bj + row0 + 32) * NN + n0 + 64 + k8];
            rb[0] = *(const int4*)&Bp[(size_t)(bk + row0) * NN + n0 + 64 + k8];
            rb[1] = *(const int4*)&Bp[(size_t)(bk + row0 + 32) * NN + n0 + 64 + k8];
        }
        #pragma unroll
        for (int h = 0; h < 2; h++) {
            bf16x8 af[2], bq[2];
            #pragma unroll
            for (int mi = 0; mi < 2; mi++)
                af[mi] = *(const bf16x8*)&As[(wj * 32 + mi * 16 + l16) * LDK + h * 32 + q * 8];
            #pragma unroll
            for (int kj = 0; kj < 2; kj++)
                bq[kj] = *(const bf16x8*)&Bs[(wk * 32 + kj * 16 + l16) * LDK + h * 32 + q * 8];
            #pragma unroll
            for (int mi = 0; mi < 2; mi++)
                #pragma unroll
                for (int kj = 0; kj < 2; kj++)
                    acc[mi][kj] = __builtin_amdgcn_mfma_f32_16x16x32_bf16(af[mi], bq[kj], acc[mi][kj], 0, 0, 0);
        }
        __syncthreads();
    }
    __syncthreads();
    #pragma unroll
    for (int mi = 0; mi < 2; mi++)
        #pragma unroll
        for (int i = 0; i < 4; i++) {
            int jl = wj * 32 + mi * 16 + q * 4 + i;
            #pragma unroll
            for (int kj = 0; kj < 2; kj++)
                Tr[jl * 68 + wk * 32 + kj * 16 + l16] = (bf16)acc[mi][kj][i];
        }
    __syncthreads();
    bf16* Mb = M2t + (size_t)b * FD * FD;
    #pragma unroll
    for (int it = 0; it < 2; it++) {
        int c = tid + it * 256;
        int r = c >> 3, chunk = c & 7;
        bf16x8 v = *(const bf16x8*)&Tr[r * 68 + chunk * 8];
        *(bf16x8*)&Mb[(size_t)(bj + r) * FD + bk + chunk * 8] = v;
    }
}

// ---------------- K4: final (R4 body; XCD-swizzled 1D grid) ----------------
__global__ __launch_bounds__(256)
void final_mfma(const bf16* __restrict__ alpha, const bf16* __restrict__ M2t,
                const float* __restrict__ dpart, const bf16* __restrict__ U2,
                const float* __restrict__ x, float* __restrict__ out)
{
    constexpr int BM = 128, BN = 64, BK = 32, LDK = 36;
    __shared__ bf16 As[BM][LDK];
    __shared__ bf16 Bs[BN][LDK];
    const int tid = threadIdx.x;
    const int wave = tid >> 6, lane = tid & 63;
    const int q = lane >> 4, l16 = lane & 15;
    const int id = blockIdx.x;
    const int by = id & 127, bx = id >> 7;
    const int bm = by * BM, bn = bx * BN;
    const bf16* Qb = M2t + (size_t)(bm >> 10) * FD * FD;

    const int rowA0 = tid >> 2,         k8A0 = (tid & 3) * 8;
    const int rowA1 = (tid + 256) >> 2, k8A1 = (tid & 3) * 8;
    const int rowB  = tid >> 2,         k8B  = (tid & 3) * 8;

    int4 ra0 = *(const int4*)&alpha[(size_t)(bm + rowA0) * FD + k8A0];
    int4 ra1 = *(const int4*)&alpha[(size_t)(bm + rowA1) * FD + k8A1];
    int4 rb  = *(const int4*)&Qb[(size_t)(bn + rowB) * FD + k8B];

    floatx4 acc[2][4] = {};
    for (int k0 = 0; k0 < FD; k0 += BK) {
        *(int4*)&As[rowA0][k8A0] = ra0;
        *(int4*)&As[rowA1][k8A1] = ra1;
        *(int4*)&Bs[rowB][k8B] = rb;
        __syncthreads();
        if (k0 + BK < FD) {
            ra0 = *(const int4*)&alpha[(size_t)(bm + rowA0) * FD + k0 + BK + k8A0];
            ra1 = *(const int4*)&alpha[(size_t)(bm + rowA1) * FD + k0 + BK + k8A1];
            rb  = *(const int4*)&Qb[(size_t)(bn + rowB) * FD + k0 + BK + k8B];
        }
        bf16x8 af[2], bq[4];
        #pragma unroll
        for (int mi = 0; mi < 2; mi++)
            af[mi] = *(const bf16x8*)&As[wave * 32 + mi * 16 + l16][q * 8];
        #pragma unroll
        for (int nj = 0; nj < 4; nj++)
            bq[nj] = *(const bf16x8*)&Bs[nj * 16 + l16][q * 8];
        #pragma unroll
        for (int mi = 0; mi < 2; mi++)
            #pragma unroll
            for (int nj = 0; nj < 4; nj++)
                acc[mi][nj] = __builtin_amdgcn_mfma_f32_16x16x32_bf16(af[mi], bq[nj], acc[mi][nj], 0, 0, 0);
        __syncthreads();
    }

    #pragma unroll
    for (int mi = 0; mi < 2; mi++)
        #pragma unroll
        for (int i = 0; i < 4; i++) {
            int m = bm + wave * 32 + mi * 16 + q * 4 + i;
            float d = dpart[m] + dpart[RR + m] + dpart[2 * RR + m] + dpart[3 * RR + m];
            #pragma unroll
            for (int nj = 0; nj < 4; nj++) {
                int n = bn + nj * 16 + l16;
                float v = (acc[mi][nj][i] - d * (float)U2[(size_t)m * FD + n]) * (1.0f / 1024.0f);
                out[(size_t)m * FD + n] = v + x[(size_t)m * FD + n];
            }
        }
}

extern "C" void kernel_launch(void* const* d_in, const int* in_sizes, int n_in,
                              void* d_out, int out_size, void* d_ws, size_t ws_size,
                              hipStream_t stream)
{
    const float* x  = (const float*)d_in[0];
    const float* Wa = (const float*)d_in[1];
    const float* Wb = (const float*)d_in[2];
    const float* Wu = (const float*)d_in[3];
    const float* bu = (const float*)d_in[4];
    const float* Wr = (const float*)d_in[5];
    float* out = (float*)d_out;

    char* w = (char*)d_ws;
    bf16* Wcb   = (bf16*)w;  w += (size_t)FD * FD * 2;
    float* bc   = (float*)w; w += (size_t)FD * 4;
    bf16* alpha = (bf16*)w;  w += (size_t)RR * FD * 2;
    bf16* U2    = (bf16*)w;  w += (size_t)RR * FD * 2;
    bf16* betaT = (bf16*)w;  w += (size_t)RR * FD * 2;
    bf16* U2T   = (bf16*)w;  w += (size_t)RR * FD * 2;
    bf16* M2t   = (bf16*)w;  w += (size_t)NB * FD * FD * 2;
    float* dpart= (float*)w; w += (size_t)4 * RR * 4;

    dim3 blk(256);

    prep<<<dim3(257), blk, 0, stream>>>(Wu, bu, Wr, Wcb, bc);

    proj3<<<dim3(512), blk, 0, stream>>>(x, Wa, Wb, Wcb,
                                         alpha, U2, betaT, U2T, bc, dpart);

    m2_mfma<<<dim3(256), blk, 0, stream>>>(U2T, betaT, M2t);

    final_mfma<<<dim3(512), blk, 0, stream>>>(alpha, M2t, dpart, U2, x, out);
}

// Round 10
// 136.411 us; speedup vs baseline: 3.7165x; 1.0510x over previous
//
#include <hip/hip_runtime.h>

// x [B=16, N=1024, F=256] fp32.  Algebra:
//   U2 = x@(Wr@Wu)^T + Wr@bu
//   M2t[b][j][k] = sum_i U2[b,i,j] * beta[b,i,k]
//   out[m,j] = (alpha[m,:].M2t[b][j,:] - d[m]*U2[m,j]) / N + x[m,j]
// K1 prep : Wcb = bf16(Wr@Wu); bc = Wr@bu   (Wa/Wb/x converted inline in proj3)
// K2 proj3: BM=128 BK=32 LDK=36 (exact R4 body, 2D grid)
// K3 m2   : BK=64, double-buffered LDS (1 sync/iter), 3D grid (no swizzle)
// K4 final: BM=128 BK=32 (exact R4 body, 2D grid)
// NOTE: dur_us includes ~80us of harness re-poison fills (measured R8: 507-428=79).

typedef __bf16 bf16;
typedef float floatx4 __attribute__((ext_vector_type(4)));
typedef bf16 bf16x8 __attribute__((ext_vector_type(8)));
typedef bf16 bf16x4 __attribute__((ext_vector_type(4)));

constexpr int FD = 256;
constexpr int NB = 16;
constexpr int NN = 1024;
constexpr int RR = NB * NN;   // 16384

__device__ __forceinline__ bf16x8 cvt8(float4 a, float4 b) {
    bf16x8 o = { (bf16)a.x, (bf16)a.y, (bf16)a.z, (bf16)a.w,
                 (bf16)b.x, (bf16)b.y, (bf16)b.z, (bf16)b.w };
    return o;
}

// ---------------- K1: prep ----------------
__global__ __launch_bounds__(256)
void prep(const float* __restrict__ Wu, const float* __restrict__ bu, const float* __restrict__ Wr,
          bf16* __restrict__ Wcb, float* __restrict__ bc)
{
    const int blk = blockIdx.x, tid = threadIdx.x;
    if (blk < 256) {  // Wc[j][f] = sum_g Wr[j][g]*Wu[g][f]; one j per block
        const int j = blk;
        float acc = 0.0f;
        for (int g = 0; g < FD; g += 4) {
            float4 wr = *(const float4*)&Wr[j * FD + g];
            acc += wr.x * Wu[g * FD + tid] + wr.y * Wu[(g + 1) * FD + tid]
                 + wr.z * Wu[(g + 2) * FD + tid] + wr.w * Wu[(g + 3) * FD + tid];
        }
        Wcb[j * FD + tid] = (bf16)acc;
    } else {  // bc[j] = Wr[j,:].bu
        float s = 0.0f;
        for (int g = 0; g < FD; g++) s += Wr[tid * FD + g] * bu[g];
        bc[tid] = s;
    }
}

// ---------------- K2: proj3 (exact R4 body) ----------------
__global__ __launch_bounds__(256)
void proj3(const float* __restrict__ x,
           const float* __restrict__ Wa, const float* __restrict__ Wb, const bf16* __restrict__ Wc,
           bf16* __restrict__ alpha, bf16* __restrict__ U2,
           bf16* __restrict__ betaT, bf16* __restrict__ U2T,
           const float* __restrict__ bc, float* __restrict__ dpart)
{
    constexpr int BM = 128, BN = 64, BK = 32, LDK = 36;
    __shared__ bf16 As[BM][LDK];
    __shared__ bf16 Bs[3][BN][LDK];
    __shared__ bf16 Tr[8960];   // natural [128][68] (8704) / transposed [64][140] (8960)
    const int tid = threadIdx.x;
    const int wave = tid >> 6, lane = tid & 63;
    const int q = lane >> 4, l16 = lane & 15;
    const int bm = blockIdx.y * BM, bn = blockIdx.x * BN;

    const int rowA0 = tid >> 2,          k8A0 = (tid & 3) * 8;
    const int rowA1 = (tid + 256) >> 2,  k8A1 = (tid & 3) * 8;
    const int rowW  = tid >> 2,          k8W  = (tid & 3) * 8;

    bf16x8 pxa0, pxa1, pwa, pwb; int4 pwc;
#define PROJ_LOAD(KK) do { \
        const float* s0 = &x[(size_t)(bm + rowA0) * FD + (KK) + k8A0]; \
        pxa0 = cvt8(*(const float4*)s0, *(const float4*)(s0 + 4)); \
        const float* s1 = &x[(size_t)(bm + rowA1) * FD + (KK) + k8A1]; \
        pxa1 = cvt8(*(const float4*)s1, *(const float4*)(s1 + 4)); \
        const float* sa = &Wa[(size_t)(bn + rowW) * FD + (KK) + k8W]; \
        pwa = cvt8(*(const float4*)sa, *(const float4*)(sa + 4)); \
        const float* sb = &Wb[(size_t)(bn + rowW) * FD + (KK) + k8W]; \
        pwb = cvt8(*(const float4*)sb, *(const float4*)(sb + 4)); \
        pwc = *(const int4*)&Wc[(size_t)(bn + rowW) * FD + (KK) + k8W]; \
    } while (0)

    floatx4 acc[3][2][4] = {};
    PROJ_LOAD(0);

    for (int k0 = 0; k0 < FD; k0 += BK) {
        *(bf16x8*)&As[rowA0][k8A0] = pxa0;
        *(bf16x8*)&As[rowA1][k8A1] = pxa1;
        *(bf16x8*)&Bs[0][rowW][k8W] = pwa;
        *(bf16x8*)&Bs[1][rowW][k8W] = pwb;
        *(int4*)&Bs[2][rowW][k8W] = pwc;
        __syncthreads();
        if (k0 + BK < FD) PROJ_LOAD(k0 + BK);
        bf16x8 af[2];
        #pragma unroll
        for (int mi = 0; mi < 2; mi++)
            af[mi] = *(const bf16x8*)&As[wave * 32 + mi * 16 + l16][q * 8];
        #pragma unroll
        for (int w = 0; w < 3; w++) {
            bf16x8 bq[4];
            #pragma unroll
            for (int nj = 0; nj < 4; nj++)
                bq[nj] = *(const bf16x8*)&Bs[w][nj * 16 + l16][q * 8];
            #pragma unroll
            for (int mi = 0; mi < 2; mi++)
                #pragma unroll
                for (int nj = 0; nj < 4; nj++)
                    acc[w][mi][nj] = __builtin_amdgcn_mfma_f32_16x16x32_bf16(af[mi], bq[nj], acc[w][mi][nj], 0, 0, 0);
        }
        __syncthreads();
    }
#undef PROJ_LOAD

    const int b = bm >> 10, n0 = bm & (NN - 1);
    float bcv[4];
    #pragma unroll
    for (int nj = 0; nj < 4; nj++) bcv[nj] = bc[bn + nj * 16 + l16];

    // diag partials
    #pragma unroll
    for (int mi = 0; mi < 2; mi++)
        #pragma unroll
        for (int i = 0; i < 4; i++) {
            float p = 0.0f;
            #pragma unroll
            for (int nj = 0; nj < 4; nj++)
                p += acc[0][mi][nj][i] * acc[1][mi][nj][i];
            #pragma unroll
            for (int off = 1; off < 16; off <<= 1) p += __shfl_xor(p, off);
            if (l16 == 0) {
                int m = bm + wave * 32 + mi * 16 + q * 4 + i;
                dpart[(size_t)blockIdx.x * RR + m] = p;
            }
        }

    // natural outputs via [128][68] repack: alpha (w=0), U2 (w=2 +bc)
    #pragma unroll
    for (int pass = 0; pass < 2; pass++) {
        const int w = pass ? 2 : 0;
        __syncthreads();
        #pragma unroll
        for (int mi = 0; mi < 2; mi++)
            #pragma unroll
            for (int i = 0; i < 4; i++) {
                int ml = wave * 32 + mi * 16 + q * 4 + i;
                #pragma unroll
                for (int nj = 0; nj < 4; nj++) {
                    float v = acc[w][mi][nj][i];
                    if (w == 2) v += bcv[nj];
                    Tr[ml * 68 + nj * 16 + l16] = (bf16)v;
                }
            }
        __syncthreads();
        bf16* dst = pass ? U2 : alpha;
        #pragma unroll
        for (int it = 0; it < 4; it++) {
            int c = tid + it * 256;
            int row = c >> 3, chunk = c & 7;
            bf16x8 v = *(const bf16x8*)&Tr[row * 68 + chunk * 8];
            *(bf16x8*)&dst[(size_t)(bm + row) * FD + bn + chunk * 8] = v;
        }
    }

    // transposed outputs via [64][140] repack: betaT (w=1), U2T (w=2 +bc)
    #pragma unroll
    for (int pass = 0; pass < 2; pass++) {
        const int w = pass ? 2 : 1;
        __syncthreads();
        #pragma unroll
        for (int mi = 0; mi < 2; mi++)
            #pragma unroll
            for (int nj = 0; nj < 4; nj++) {
                bf16x4 v4;
                #pragma unroll
                for (int i = 0; i < 4; i++) {
                    float v = acc[w][mi][nj][i];
                    if (w == 2) v += bcv[nj];
                    v4[i] = (bf16)v;
                }
                *(bf16x4*)&Tr[(nj * 16 + l16) * 140 + wave * 32 + mi * 16 + q * 4] = v4;
            }
        __syncthreads();
        bf16* dst = (pass ? U2T : betaT) + (size_t)b * FD * NN;
        #pragma unroll
        for (int it = 0; it < 4; it++) {
            int c = tid + it * 256;
            int row = c >> 4, chunk = c & 15;
            bf16x8 v = *(const bf16x8*)&Tr[row * 140 + chunk * 8];
            *(bf16x8*)&dst[(size_t)(bn + row) * NN + n0 + chunk * 8] = v;
        }
    }
}

// ---------------- K3: m2 (BK=64, double-buffered, 1 sync/iter; 3D grid) ----------------
__global__ __launch_bounds__(256)
void m2_mfma(const bf16* __restrict__ U2T, const bf16* __restrict__ betaT, bf16* __restrict__ M2t)
{
    constexpr int LDK = 68;
    __shared__ __align__(16) bf16 As[2][64 * LDK];   // 2 x 8704 B
    __shared__ __align__(16) bf16 Bs[2][64 * LDK];
    bf16* Tr = As[0];                                // aliased; guarded by sync below
    const int tid = threadIdx.x;
    const int wave = tid >> 6, lane = tid & 63;
    const int q = lane >> 4, l16 = lane & 15;
    const int wj = wave >> 1, wk = wave & 1;
    const int b = blockIdx.z;
    const int bj = blockIdx.y * 64, bk = blockIdx.x * 64;
    const int row0 = tid >> 3, k8 = (tid & 7) * 8;
    const bf16* Ap = U2T + (size_t)b * FD * NN;
    const bf16* Bp = betaT + (size_t)b * FD * NN;

    int4 ra[2], rb[2];
    ra[0] = *(const int4*)&Ap[(size_t)(bj + row0) * NN + k8];
    ra[1] = *(const int4*)&Ap[(size_t)(bj + row0 + 32) * NN + k8];
    rb[0] = *(const int4*)&Bp[(size_t)(bk + row0) * NN + k8];
    rb[1] = *(const int4*)&Bp[(size_t)(bk + row0 + 32) * NN + k8];

    floatx4 acc[2][2] = {};
    int p = 0;
    for (int n0 = 0; n0 < NN; n0 += 64) {
        *(int4*)&As[p][row0 * LDK + k8] = ra[0];
        *(int4*)&As[p][(row0 + 32) * LDK + k8] = ra[1];
        *(int4*)&Bs[p][row0 * LDK + k8] = rb[0];
        *(int4*)&Bs[p][(row0 + 32) * LDK + k8] = rb[1];
        if (n0 + 64 < NN) {
            ra[0] = *(const int4*)&Ap[(size_t)(bj + row0) * NN + n0 + 64 + k8];
            ra[1] = *(const int4*)&Ap[(size_t)(bj + row0 + 32) * NN + n0 + 64 + k8];
            rb[0] = *(const int4*)&Bp[(size_t)(bk + row0) * NN + n0 + 64 + k8];
            rb[1] = *(const int4*)&Bp[(size_t)(bk + row0 + 32) * NN + n0 + 64 + k8];
        }
        __syncthreads();
        #pragma unroll
        for (int h = 0; h < 2; h++) {
            bf16x8 af[2], bq[2];
            #pragma unroll
            for (int mi = 0; mi < 2; mi++)
                af[mi] = *(const bf16x8*)&As[p][(wj * 32 + mi * 16 + l16) * LDK + h * 32 + q * 8];
            #pragma unroll
            for (int kj = 0; kj < 2; kj++)
                bq[kj] = *(const bf16x8*)&Bs[p][(wk * 32 + kj * 16 + l16) * LDK + h * 32 + q * 8];
            #pragma unroll
            for (int mi = 0; mi < 2; mi++)
                #pragma unroll
                for (int kj = 0; kj < 2; kj++)
                    acc[mi][kj] = __builtin_amdgcn_mfma_f32_16x16x32_bf16(af[mi], bq[kj], acc[mi][kj], 0, 0, 0);
        }
        p ^= 1;
        // no trailing sync: next iter writes the other buffer; by the time any
        // wave re-writes this buffer (2 iters later) all waves have passed the
        // intervening sync having completed their reads.
    }
    __syncthreads();   // drain last MFMA reads before Tr (aliases As[0]) is overwritten
    #pragma unroll
    for (int mi = 0; mi < 2; mi++)
        #pragma unroll
        for (int i = 0; i < 4; i++) {
            int jl = wj * 32 + mi * 16 + q * 4 + i;
            #pragma unroll
            for (int kj = 0; kj < 2; kj++)
                Tr[jl * 68 + wk * 32 + kj * 16 + l16] = (bf16)acc[mi][kj][i];
        }
    __syncthreads();
    bf16* Mb = M2t + (size_t)b * FD * FD;
    #pragma unroll
    for (int it = 0; it < 2; it++) {
        int c = tid + it * 256;
        int r = c >> 3, chunk = c & 7;
        bf16x8 v = *(const bf16x8*)&Tr[r * 68 + chunk * 8];
        *(bf16x8*)&Mb[(size_t)(bj + r) * FD + bk + chunk * 8] = v;
    }
}

// ---------------- K4: final (exact R4 body) ----------------
__global__ __launch_bounds__(256)
void final_mfma(const bf16* __restrict__ alpha, const bf16* __restrict__ M2t,
                const float* __restrict__ dpart, const bf16* __restrict__ U2,
                const float* __restrict__ x, float* __restrict__ out)
{
    constexpr int BM = 128, BN = 64, BK = 32, LDK = 36;
    __shared__ bf16 As[BM][LDK];
    __shared__ bf16 Bs[BN][LDK];
    const int tid = threadIdx.x;
    const int wave = tid >> 6, lane = tid & 63;
    const int q = lane >> 4, l16 = lane & 15;
    const int bm = blockIdx.y * BM, bn = blockIdx.x * BN;
    const bf16* Qb = M2t + (size_t)(bm >> 10) * FD * FD;

    const int rowA0 = tid >> 2,         k8A0 = (tid & 3) * 8;
    const int rowA1 = (tid + 256) >> 2, k8A1 = (tid & 3) * 8;
    const int rowB  = tid >> 2,         k8B  = (tid & 3) * 8;

    int4 ra0 = *(const int4*)&alpha[(size_t)(bm + rowA0) * FD + k8A0];
    int4 ra1 = *(const int4*)&alpha[(size_t)(bm + rowA1) * FD + k8A1];
    int4 rb  = *(const int4*)&Qb[(size_t)(bn + rowB) * FD + k8B];

    floatx4 acc[2][4] = {};
    for (int k0 = 0; k0 < FD; k0 += BK) {
        *(int4*)&As[rowA0][k8A0] = ra0;
        *(int4*)&As[rowA1][k8A1] = ra1;
        *(int4*)&Bs[rowB][k8B] = rb;
        __syncthreads();
        if (k0 + BK < FD) {
            ra0 = *(const int4*)&alpha[(size_t)(bm + rowA0) * FD + k0 + BK + k8A0];
            ra1 = *(const int4*)&alpha[(size_t)(bm + rowA1) * FD + k0 + BK + k8A1];
            rb  = *(const int4*)&Qb[(size_t)(bn + rowB) * FD + k0 + BK + k8B];
        }
        bf16x8 af[2], bq[4];
        #pragma unroll
        for (int mi = 0; mi < 2; mi++)
            af[mi] = *(const bf16x8*)&As[wave * 32 + mi * 16 + l16][q * 8];
        #pragma unroll
        for (int nj = 0; nj < 4; nj++)
            bq[nj] = *(const bf16x8*)&Bs[nj * 16 + l16][q * 8];
        #pragma unroll
        for (int mi = 0; mi < 2; mi++)
            #pragma unroll
            for (int nj = 0; nj < 4; nj++)
                acc[mi][nj] = __builtin_amdgcn_mfma_f32_16x16x32_bf16(af[mi], bq[nj], acc[mi][nj], 0, 0, 0);
        __syncthreads();
    }

    #pragma unroll
    for (int mi = 0; mi < 2; mi++)
        #pragma unroll
        for (int i = 0; i < 4; i++) {
            int m = bm + wave * 32 + mi * 16 + q * 4 + i;
            float d = dpart[m] + dpart[RR + m] + dpart[2 * RR + m] + dpart[3 * RR + m];
            #pragma unroll
            for (int nj = 0; nj < 4; nj++) {
                int n = bn + nj * 16 + l16;
                float v = (acc[mi][nj][i] - d * (float)U2[(size_t)m * FD + n]) * (1.0f / 1024.0f);
                out[(size_t)m * FD + n] = v + x[(size_t)m * FD + n];
            }
        }
}

extern "C" void kernel_launch(void* const* d_in, const int* in_sizes, int n_in,
                              void* d_out, int out_size, void* d_ws, size_t ws_size,
                              hipStream_t stream)
{
    const float* x  = (const float*)d_in[0];
    const float* Wa = (const float*)d_in[1];
    const float* Wb = (const float*)d_in[2];
    const float* Wu = (const float*)d_in[3];
    const float* bu = (const float*)d_in[4];
    const float* Wr = (const float*)d_in[5];
    float* out = (float*)d_out;

    char* w = (char*)d_ws;
    bf16* Wcb   = (bf16*)w;  w += (size_t)FD * FD * 2;
    float* bc   = (float*)w; w += (size_t)FD * 4;
    bf16* alpha = (bf16*)w;  w += (size_t)RR * FD * 2;
    bf16* U2    = (bf16*)w;  w += (size_t)RR * FD * 2;
    bf16* betaT = (bf16*)w;  w += (size_t)RR * FD * 2;
    bf16* U2T   = (bf16*)w;  w += (size_t)RR * FD * 2;
    bf16* M2t   = (bf16*)w;  w += (size_t)NB * FD * FD * 2;
    float* dpart= (float*)w; w += (size_t)4 * RR * 4;

    dim3 blk(256);

    prep<<<dim3(257), blk, 0, stream>>>(Wu, bu, Wr, Wcb, bc);

    proj3<<<dim3(FD / 64, RR / 128), blk, 0, stream>>>(x, Wa, Wb, Wcb,
                                                       alpha, U2, betaT, U2T, bc, dpart);

    m2_mfma<<<dim3(FD / 64, FD / 64, NB), blk, 0, stream>>>(U2T, betaT, M2t);

    final_mfma<<<dim3(FD / 64, RR / 128), blk, 0, stream>>>(alpha, M2t, dpart, U2, x, out);
}